// Round 5
// baseline (5516.682 us; speedup 1.0000x reference)
//
#include <hip/hip_runtime.h>
#include <hip/hip_cooperative_groups.h>
#include <math.h>

namespace cg = cooperative_groups;

#define NITEMS 50000
#define NROWS 50001
#define DD 512
#define HH 512
#define TT 16
#define NEGV (-1e18f)
#define NB 256          // cooperative grid blocks (1 per CU guaranteed)
#define NT 512          // threads per block (8 waves)
#define NWAVES (NB * 8) // 2048

// fallback (discrete) geometry
#define NWAVE_HOP 4096
#define NBLK_ATTN 2048

// ---- order-preserving float <-> uint key ----
__device__ __forceinline__ unsigned fkey(float f) {
  unsigned u = __float_as_uint(f);
  return (u & 0x80000000u) ? ~u : (u | 0x80000000u);
}

// fast tanh / exp via v_exp_f32 + v_rcp_f32
__device__ __forceinline__ float ftanh(float x) {
  float e = __builtin_amdgcn_exp2f(x * 2.885390081777927f);  // exp(2x)
  return 1.f - 2.f * __builtin_amdgcn_rcpf(e + 1.f);
}
__device__ __forceinline__ float fexp(float x) {
  return __builtin_amdgcn_exp2f(x * 1.4426950408889634f);
}

// ---------------- feat = mem @ W ----------------
__launch_bounds__(256)
__global__ void k_feat_gemm(const float* __restrict__ A0, const float* __restrict__ stoprow,
                            const float* __restrict__ B, float* __restrict__ C) {
  __shared__ float As[8][128];
  __shared__ float Bs[8][128];
  const int tid = threadIdx.x;
  const int m0 = blockIdx.y * 128, n0 = blockIdx.x * 128;
  const int tx = tid & 15, ty = tid >> 4;
  const int ar = tid >> 1, ak = (tid & 1) * 4;
  const int bk = tid >> 5, bc = (tid & 31) * 4;
  const int arow = m0 + ar;
  const float* Arow = (arow < NITEMS) ? (A0 + (size_t)arow * DD) : stoprow;
  const bool avalid = (arow < NROWS);
  float acc[8][8];
#pragma unroll
  for (int i = 0; i < 8; ++i)
#pragma unroll
    for (int j = 0; j < 8; ++j) acc[i][j] = 0.f;

  for (int kt = 0; kt < DD; kt += 8) {
    float4 av = avalid ? *(const float4*)(Arow + kt + ak) : make_float4(0.f, 0.f, 0.f, 0.f);
    As[ak + 0][ar] = av.x;
    As[ak + 1][ar] = av.y;
    As[ak + 2][ar] = av.z;
    As[ak + 3][ar] = av.w;
    *(float4*)&Bs[bk][bc] = *(const float4*)(B + (size_t)(kt + bk) * HH + n0 + bc);
    __syncthreads();
#pragma unroll
    for (int k = 0; k < 8; ++k) {
      float a[8], b[8];
      *(float4*)&a[0] = *(const float4*)&As[k][ty * 8];
      *(float4*)&a[4] = *(const float4*)&As[k][ty * 8 + 4];
      *(float4*)&b[0] = *(const float4*)&Bs[k][tx * 4];
      *(float4*)&b[4] = *(const float4*)&Bs[k][64 + tx * 4];
#pragma unroll
      for (int i = 0; i < 8; ++i)
#pragma unroll
        for (int j = 0; j < 8; ++j) acc[i][j] = fmaf(a[i], b[j], acc[i][j]);
    }
    __syncthreads();
  }
#pragma unroll
  for (int i = 0; i < 8; ++i) {
    int row = m0 + ty * 8 + i;
    if (row < NROWS) {
      float* crow = C + (size_t)row * HH + n0;
      *(float4*)(crow + tx * 4) = make_float4(acc[i][0], acc[i][1], acc[i][2], acc[i][3]);
      *(float4*)(crow + 64 + tx * 4) = make_float4(acc[i][4], acc[i][5], acc[i][6], acc[i][7]);
    }
  }
}

// ======================================================================
//                     COOPERATIVE MEGA-KERNEL PATH
// ======================================================================
struct P {
  const float *attn_mem, *stoprow, *init_h, *init_c, *init_i;
  const float *attn_wq, *attn_v, *hop_wq, *hop_v;
  const float *w_ih, *w_hh, *b_ih, *b_hh, *gumbel;
  const float *attn_feat, *hop_feat;
  float* sc;
  int* sel;
  float *qp, *bmh, *bZh, *bma, *bZa;
  unsigned long long* bkey;
  float *gates, *hv, *cv0, *cv1, *b1, *b2;
  int *done2, *xrow2;
  float* outf;
};

union SM {
  struct { float qbuf[8][NT]; float smax[8]; float sz[8]; } d;
  struct { float rm[NT]; float rz[NT]; unsigned long long rk[NT]; } r;
  struct { float h[512]; float red[512]; } bc;
  struct { float cf[NB]; float qn[512]; float red[512]; } ef;
  struct { float wm[8]; float wz[8]; unsigned long long wk[8]; } g;
};

// deterministic block-wide reduce of NB (M, Z, key) partials (512 threads)
__device__ void reduce_final(const float* __restrict__ bm, const float* __restrict__ bZ,
                             const unsigned long long* __restrict__ bk, SM& sm, int tid,
                             float& M, float& Z, unsigned long long& K) {
  sm.r.rm[tid] = (tid < NB) ? bm[tid] : -3.0e38f;
  sm.r.rk[tid] = (tid < NB) ? bk[tid] : 0ull;
  __syncthreads();
  for (int s = 256; s > 0; s >>= 1) {
    if (tid < s) {
      sm.r.rm[tid] = fmaxf(sm.r.rm[tid], sm.r.rm[tid + s]);
      if (sm.r.rk[tid + s] > sm.r.rk[tid]) sm.r.rk[tid] = sm.r.rk[tid + s];
    }
    __syncthreads();
  }
  M = sm.r.rm[0];
  K = sm.r.rk[0];
  __syncthreads();
  sm.r.rz[tid] = (tid < NB) ? bZ[tid] * expf(bm[tid] - M) : 0.f;
  __syncthreads();
  for (int s = 256; s > 0; s >>= 1) {
    if (tid < s) sm.r.rz[tid] += sm.r.rz[tid + s];
    __syncthreads();
  }
  Z = sm.r.rz[0];
  __syncthreads();
}

__launch_bounds__(NT, 2)
__global__ void k_loop(P p) {
  cg::grid_group grid = cg::this_grid();
  __shared__ SM sm;
  const int tid = threadIdx.x;
  const int blk = blockIdx.x;
  const int w = tid >> 6, lane = tid & 63;

  // ---- prologue: zero sel ----
  {
    int g = blk * NT + tid;
    if (g < NROWS) p.sel[g] = 0;
  }
  grid.sync();

  for (int t = 0; t < TT; ++t) {
    // ===== phase HA: finalize step t-1 (redundant in all blocks) + LSTM gates =====
    {
      int xrow = -1;
      if (t > 0) {
        float M, Z;
        unsigned long long K;
        reduce_final(p.bma, p.bZa, p.bkey, sm, tid, M, Z, K);
        const int out = NITEMS - (int)(unsigned)(K & 0xffffffffull);
        const int d_in = (t == 1) ? 0 : p.done2[(t - 1) & 1];
        const int xprev = (t == 1) ? -1 : p.xrow2[(t - 1) & 1];
        const int nd = d_in | (out == NITEMS);
        xrow = nd ? xprev : out;
        if (blk == 0 && tid == 0) {
          p.outf[t - 1] = (float)(d_in ? NITEMS : out);
          p.outf[TT + t - 1] = d_in ? 0.f : (p.sc[out] - M - logf(Z));
          if (!d_in) p.sel[out] = 1;
          p.done2[t & 1] = nd;
          p.xrow2[t & 1] = xrow;
        }
      }
      // LSTM gates: wave w of block blk -> gate row r (256 blocks x 8 waves = 2048 rows)
      const int r = blk * 8 + w;
      const float* xp = (xrow < 0) ? p.init_i
                                   : ((xrow == NITEMS) ? p.stoprow : p.attn_mem + (size_t)xrow * DD);
      const float* hp = (t == 0) ? p.init_h : p.hv;
      const float4* x4 = (const float4*)xp;
      const float4* h4 = (const float4*)hp;
      const float4* wi = (const float4*)(p.w_ih + (size_t)r * DD);
      const float4* wh = (const float4*)(p.w_hh + (size_t)r * DD);
      float s = 0.f;
      float4 a, ww;
      a = x4[lane * 2];     ww = wi[lane * 2];     s += a.x * ww.x + a.y * ww.y + a.z * ww.z + a.w * ww.w;
      a = x4[lane * 2 + 1]; ww = wi[lane * 2 + 1]; s += a.x * ww.x + a.y * ww.y + a.z * ww.z + a.w * ww.w;
      a = h4[lane * 2];     ww = wh[lane * 2];     s += a.x * ww.x + a.y * ww.y + a.z * ww.z + a.w * ww.w;
      a = h4[lane * 2 + 1]; ww = wh[lane * 2 + 1]; s += a.x * ww.x + a.y * ww.y + a.z * ww.z + a.w * ww.w;
#pragma unroll
      for (int off = 32; off > 0; off >>= 1) s += __shfl_xor(s, off);
      if (lane == 0) p.gates[r] = s + p.b_ih[r] + p.b_hh[r];
    }
    grid.sync();

    // ===== phase BC: h,c update (redundant in 8 blocks) + b1 = h @ hop_wq =====
    if (blk < 8) {
      const float* csrc = (t == 0) ? p.init_c : ((t & 1) ? p.cv1 : p.cv0);
      float* cdst = (t & 1) ? p.cv0 : p.cv1;
      const float gi = p.gates[tid], gf = p.gates[HH + tid], gg = p.gates[2 * HH + tid],
                  go = p.gates[3 * HH + tid];
      const float si = 1.f / (1.f + expf(-gi));
      const float sf = 1.f / (1.f + expf(-gf));
      const float so = 1.f / (1.f + expf(-go));
      const float cn = sf * csrc[tid] + si * tanhf(gg);
      const float hval = so * tanhf(cn);
      sm.bc.h[tid] = hval;
      if (blk == 0) { cdst[tid] = cn; p.hv[tid] = hval; }
      __syncthreads();
      const int c = tid & 63, q = tid >> 6, j0 = blk * 64;
      float pb = 0.f;
      for (int i = q * 64; i < q * 64 + 64; ++i)
        pb = fmaf(sm.bc.h[i], p.hop_wq[(size_t)i * HH + j0 + c], pb);
      sm.bc.red[tid] = pb;
      __syncthreads();
      if (tid < 64) {
        float acc = 0.f;
#pragma unroll
        for (int g2 = 0; g2 < 8; ++g2) acc += sm.bc.red[tid + 64 * g2];
        p.b1[j0 + tid] = acc;
      }
    }
    grid.sync();

    // ===== phase D: hop pass (all 2048 waves) =====
    {
      float bv[8], vv[8], qa[8];
#pragma unroll
      for (int j = 0; j < 8; ++j) {
        bv[j] = p.b1[lane * 8 + j];
        vv[j] = p.hop_v[lane * 8 + j];
        qa[j] = 0.f;
      }
      float M = -3.0e38f, Z = 0.f;
      const int wv = blk * 8 + w;
      for (int m = wv; m < NROWS; m += NWAVES) {
        const float4* fp = (const float4*)(p.hop_feat + (size_t)m * HH);
        float4 A = fp[lane * 2], B = fp[lane * 2 + 1];
        float f[8] = {A.x, A.y, A.z, A.w, B.x, B.y, B.z, B.w};
        float s = 0.f;
#pragma unroll
        for (int j = 0; j < 8; ++j) s += ftanh(f[j] + bv[j]) * vv[j];
#pragma unroll
        for (int off = 32; off > 0; off >>= 1) s += __shfl_xor(s, off);
        const float Mn = fmaxf(M, s);
        const float scale = fexp(M - Mn), e = fexp(s - Mn);
        Z = Z * scale + e;
#pragma unroll
        for (int j = 0; j < 8; ++j) qa[j] = fmaf(e, f[j], qa[j] * scale);
        M = Mn;
      }
      if (lane == 0) { sm.d.smax[w] = M; sm.d.sz[w] = Z; }
      __syncthreads();
      float Mb = sm.d.smax[0];
#pragma unroll
      for (int j = 1; j < 8; ++j) Mb = fmaxf(Mb, sm.d.smax[j]);
      const float sw = expf(M - Mb);
#pragma unroll
      for (int j = 0; j < 8; ++j) sm.d.qbuf[w][lane * 8 + j] = qa[j] * sw;
      __syncthreads();
      float acc = 0.f;
#pragma unroll
      for (int w2 = 0; w2 < 8; ++w2) acc += sm.d.qbuf[w2][tid];
      p.qp[(size_t)blk * HH + tid] = acc;
      if (tid == 0) {
        float Zb = 0.f;
#pragma unroll
        for (int w2 = 0; w2 < 8; ++w2) Zb += sm.d.sz[w2] * expf(sm.d.smax[w2] - Mb);
        p.bmh[blk] = Mb;
        p.bZh[blk] = Zb;
      }
    }
    grid.sync();

    // ===== phase EF: qn combine (redundant in 8 blocks) + b2 = qn @ attn_wq =====
    if (blk < 8) {
      sm.ef.red[tid] = (tid < NB) ? p.bmh[tid] : -3.0e38f;
      __syncthreads();
      for (int s = 256; s > 0; s >>= 1) {
        if (tid < s) sm.ef.red[tid] = fmaxf(sm.ef.red[tid], sm.ef.red[tid + s]);
        __syncthreads();
      }
      const float Mg = sm.ef.red[0];
      __syncthreads();
      float c0 = 0.f;
      if (tid < NB) {
        c0 = expf(p.bmh[tid] - Mg);
        sm.ef.cf[tid] = c0;
      }
      sm.ef.red[tid] = (tid < NB) ? p.bZh[tid] * c0 : 0.f;
      __syncthreads();
      for (int s = 256; s > 0; s >>= 1) {
        if (tid < s) sm.ef.red[tid] += sm.ef.red[tid + s];
        __syncthreads();
      }
      const float Z = sm.ef.red[0];
      __syncthreads();
      float acc = 0.f;
#pragma unroll 8
      for (int pp = 0; pp < NB; ++pp) acc = fmaf(sm.ef.cf[pp], p.qp[(size_t)pp * HH + tid], acc);
      sm.ef.qn[tid] = acc / Z;
      __syncthreads();
      const int c = tid & 63, q = tid >> 6, j0 = blk * 64;
      float pb = 0.f;
      for (int i = q * 64; i < q * 64 + 64; ++i)
        pb = fmaf(sm.ef.qn[i], p.attn_wq[(size_t)i * HH + j0 + c], pb);
      sm.ef.red[tid] = pb;
      __syncthreads();
      if (tid < 64) {
        float a2 = 0.f;
#pragma unroll
        for (int g2 = 0; g2 < 8; ++g2) a2 += sm.ef.red[tid + 64 * g2];
        p.b2[j0 + tid] = a2;
      }
    }
    grid.sync();

    // ===== phase G: attn pass (all 2048 waves) =====
    {
      float bv[8], vv[8];
#pragma unroll
      for (int j = 0; j < 8; ++j) {
        bv[j] = p.b2[lane * 8 + j];
        vv[j] = p.attn_v[lane * 8 + j];
      }
      float M = -3.0e38f, Z = 0.f;
      unsigned long long kb = 0ull;
      const float* gum = p.gumbel + (size_t)t * NROWS;
      const int wv = blk * 8 + w;
      for (int m = wv; m < NROWS; m += NWAVES) {
        float s;
        if (p.sel[m]) {
          s = NEGV;
        } else {
          const float4* fp = (const float4*)(p.attn_feat + (size_t)m * HH);
          float4 A = fp[lane * 2], B = fp[lane * 2 + 1];
          s  = ftanh(A.x + bv[0]) * vv[0];
          s += ftanh(A.y + bv[1]) * vv[1];
          s += ftanh(A.z + bv[2]) * vv[2];
          s += ftanh(A.w + bv[3]) * vv[3];
          s += ftanh(B.x + bv[4]) * vv[4];
          s += ftanh(B.y + bv[5]) * vv[5];
          s += ftanh(B.z + bv[6]) * vv[6];
          s += ftanh(B.w + bv[7]) * vv[7];
#pragma unroll
          for (int off = 32; off > 0; off >>= 1) s += __shfl_xor(s, off);
        }
        if (lane == 0) p.sc[m] = s;
        const float Mn = fmaxf(M, s);
        Z = Z * fexp(M - Mn) + fexp(s - Mn);
        M = Mn;
        const float svg = s + gum[m];
        const unsigned long long key =
            ((unsigned long long)fkey(svg) << 32) | (unsigned)(NITEMS - m);
        if (key > kb) kb = key;
      }
      if (lane == 0) { sm.g.wm[w] = M; sm.g.wz[w] = Z; sm.g.wk[w] = kb; }
      __syncthreads();
      if (tid == 0) {
        float Mb = sm.g.wm[0];
#pragma unroll
        for (int j = 1; j < 8; ++j) Mb = fmaxf(Mb, sm.g.wm[j]);
        float Zb = 0.f;
#pragma unroll
        for (int j = 0; j < 8; ++j) Zb += sm.g.wz[j] * expf(sm.g.wm[j] - Mb);
        unsigned long long kbb = sm.g.wk[0];
#pragma unroll
        for (int j = 1; j < 8; ++j)
          if (sm.g.wk[j] > kbb) kbb = sm.g.wk[j];
        p.bma[blk] = Mb;
        p.bZa[blk] = Zb;
        p.bkey[blk] = kbb;
      }
    }
    grid.sync();
  }

  // ---- final: step 15 outputs ----
  if (blk == 0) {
    float M, Z;
    unsigned long long K;
    reduce_final(p.bma, p.bZa, p.bkey, sm, tid, M, Z, K);
    if (tid == 0) {
      const int out = NITEMS - (int)(unsigned)(K & 0xffffffffull);
      const int d_in = p.done2[(TT - 1) & 1];
      p.outf[TT - 1] = (float)(d_in ? NITEMS : out);
      p.outf[2 * TT - 1] = d_in ? 0.f : (p.sc[out] - M - logf(Z));
    }
  }
}

// ======================================================================
//                     DISCRETE FALLBACK PATH (R3, verified)
// ======================================================================
__global__ void k_init(int* __restrict__ sel, float* __restrict__ x, float* __restrict__ h,
                       float* __restrict__ c, int* __restrict__ done,
                       const float* __restrict__ init_i, const float* __restrict__ init_h,
                       const float* __restrict__ init_c) {
  int i = blockIdx.x * blockDim.x + threadIdx.x;
  if (i < NROWS) sel[i] = 0;
  if (i < HH) { x[i] = init_i[i]; h[i] = init_h[i]; c[i] = init_c[i]; }
  if (i == 0) *done = 0;
}

__launch_bounds__(256)
__global__ void k_lstm_step(const float* __restrict__ x, const float* __restrict__ hin,
                            float* __restrict__ hout, float* __restrict__ c,
                            const float* __restrict__ w_ih, const float* __restrict__ w_hh,
                            const float* __restrict__ b_ih, const float* __restrict__ b_hh) {
  __shared__ float g4[4];
  const int tid = threadIdx.x;
  const int w = tid >> 6, lane = tid & 63;
  const int b = blockIdx.x;
  const int r = w * HH + b;
  const float4* wi = (const float4*)(w_ih + (size_t)r * DD);
  const float4* wh = (const float4*)(w_hh + (size_t)r * DD);
  const float4* x4 = (const float4*)x;
  const float4* h4 = (const float4*)hin;
  float s = 0.f;
  float4 a, ww;
  a = x4[lane * 2];     ww = wi[lane * 2];     s += a.x * ww.x + a.y * ww.y + a.z * ww.z + a.w * ww.w;
  a = x4[lane * 2 + 1]; ww = wi[lane * 2 + 1]; s += a.x * ww.x + a.y * ww.y + a.z * ww.z + a.w * ww.w;
  a = h4[lane * 2];     ww = wh[lane * 2];     s += a.x * ww.x + a.y * ww.y + a.z * ww.z + a.w * ww.w;
  a = h4[lane * 2 + 1]; ww = wh[lane * 2 + 1]; s += a.x * ww.x + a.y * ww.y + a.z * ww.z + a.w * ww.w;
#pragma unroll
  for (int off = 32; off > 0; off >>= 1) s += __shfl_xor(s, off);
  if (lane == 0) g4[w] = s + b_ih[r] + b_hh[r];
  __syncthreads();
  if (tid == 0) {
    float si = 1.f / (1.f + expf(-g4[0]));
    float sf = 1.f / (1.f + expf(-g4[1]));
    float gg = g4[2];
    float so = 1.f / (1.f + expf(-g4[3]));
    float cn = sf * c[b] + si * tanhf(gg);
    c[b] = cn;
    hout[b] = so * tanhf(cn);
  }
}

__launch_bounds__(256)
__global__ void k_gemv(const float* __restrict__ q, const float* __restrict__ W,
                       float* __restrict__ out) {
  __shared__ float lds[256];
  const int tid = threadIdx.x;
  const int cc = tid & 63, rs = tid >> 6;
  const int j = blockIdx.x * 64 + cc;
  float p = 0.f;
  for (int i = rs * 128; i < rs * 128 + 128; ++i) p += q[i] * W[(size_t)i * HH + j];
  lds[tid] = p;
  __syncthreads();
  if (tid < 64) out[blockIdx.x * 64 + tid] = lds[tid] + lds[tid + 64] + lds[tid + 128] + lds[tid + 192];
}

__launch_bounds__(256)
__global__ void k_hop_fused(const float* __restrict__ feat, const float* __restrict__ bvec,
                            const float* __restrict__ v, float* __restrict__ qp,
                            float* __restrict__ bm, float* __restrict__ bZ) {
  const int tid = threadIdx.x;
  const int w = tid >> 6, lane = tid & 63;
  const int wv = blockIdx.x * 4 + w;
  float bv[8], vv[8], qa[8];
#pragma unroll
  for (int j = 0; j < 8; ++j) { bv[j] = bvec[lane * 8 + j]; vv[j] = v[lane * 8 + j]; qa[j] = 0.f; }
  float M = -3.0e38f, Z = 0.f;
  for (int m = wv; m < NROWS; m += NWAVE_HOP) {
    const float4* fp = (const float4*)(feat + (size_t)m * HH);
    float4 A = fp[lane * 2], B = fp[lane * 2 + 1];
    float f[8] = {A.x, A.y, A.z, A.w, B.x, B.y, B.z, B.w};
    float s = 0.f;
#pragma unroll
    for (int j = 0; j < 8; ++j) s += ftanh(f[j] + bv[j]) * vv[j];
#pragma unroll
    for (int off = 32; off > 0; off >>= 1) s += __shfl_xor(s, off);
    const float Mn = fmaxf(M, s);
    const float scale = fexp(M - Mn);
    const float e = fexp(s - Mn);
    Z = Z * scale + e;
#pragma unroll
    for (int j = 0; j < 8; ++j) qa[j] = fmaf(e, f[j], qa[j] * scale);
    M = Mn;
  }
  float4* qpo = (float4*)(qp + (size_t)wv * HH + lane * 8);
  qpo[0] = make_float4(qa[0], qa[1], qa[2], qa[3]);
  qpo[1] = make_float4(qa[4], qa[5], qa[6], qa[7]);
  if (lane == 0) { bm[wv] = M; bZ[wv] = Z; }
}

__launch_bounds__(1024)
__global__ void k_hop_qn(const float* __restrict__ qp, const float* __restrict__ bm,
                         const float* __restrict__ bZ, float* __restrict__ qn) {
  __shared__ float red[1024];
  __shared__ float cf[NWAVE_HOP];
  const int tid = threadIdx.x;
  float m0 = fmaxf(fmaxf(bm[tid], bm[tid + 1024]), fmaxf(bm[tid + 2048], bm[tid + 3072]));
  red[tid] = m0;
  __syncthreads();
  for (int s2 = 512; s2 > 0; s2 >>= 1) {
    if (tid < s2) red[tid] = fmaxf(red[tid], red[tid + s2]);
    __syncthreads();
  }
  const float Mg = red[0];
  __syncthreads();
  float zz = 0.f;
#pragma unroll
  for (int j = 0; j < 4; ++j) {
    float cc = expf(bm[tid + 1024 * j] - Mg);
    cf[tid + 1024 * j] = cc;
    zz += bZ[tid + 1024 * j] * cc;
  }
  red[tid] = zz;
  __syncthreads();
  for (int s2 = 512; s2 > 0; s2 >>= 1) {
    if (tid < s2) red[tid] += red[tid + s2];
    __syncthreads();
  }
  const float Z = red[0];
  __syncthreads();
  const int cc = tid & 31, q = tid >> 5;
  const int col = blockIdx.x * 32 + cc;
  float acc = 0.f;
  for (int p = q * 128; p < q * 128 + 128; ++p) acc = fmaf(cf[p], qp[(size_t)p * HH + col], acc);
  red[tid] = acc;
  __syncthreads();
  if (tid < 32) {
    float a = 0.f;
#pragma unroll
    for (int g = 0; g < 32; ++g) a += red[tid + 32 * g];
    qn[blockIdx.x * 32 + tid] = a / Z;
  }
}

__launch_bounds__(256)
__global__ void k_attn_fused(const float* __restrict__ feat, const float* __restrict__ bvec,
                             const float* __restrict__ v, const int* __restrict__ sel,
                             const float* __restrict__ gum, float* __restrict__ sc,
                             float* __restrict__ bm, float* __restrict__ bZ,
                             unsigned long long* __restrict__ bkey) {
  __shared__ float wm[4], wz[4];
  __shared__ unsigned long long wk[4];
  const int tid = threadIdx.x;
  const int w = tid >> 6, lane = tid & 63;
  const int wv = blockIdx.x * 4 + w;
  float bv[8], vv[8];
#pragma unroll
  for (int j = 0; j < 8; ++j) { bv[j] = bvec[lane * 8 + j]; vv[j] = v[lane * 8 + j]; }
  float M = -3.0e38f, Z = 0.f;
  unsigned long long kbest = 0ull;

  for (int m = wv; m < NROWS; m += 4 * NBLK_ATTN) {
    float s;
    if (sel[m]) {
      s = NEGV;
    } else {
      const float4* fp = (const float4*)(feat + (size_t)m * HH);
      float4 A = fp[lane * 2], B = fp[lane * 2 + 1];
      s  = ftanh(A.x + bv[0]) * vv[0];
      s += ftanh(A.y + bv[1]) * vv[1];
      s += ftanh(A.z + bv[2]) * vv[2];
      s += ftanh(A.w + bv[3]) * vv[3];
      s += ftanh(B.x + bv[4]) * vv[4];
      s += ftanh(B.y + bv[5]) * vv[5];
      s += ftanh(B.z + bv[6]) * vv[6];
      s += ftanh(B.w + bv[7]) * vv[7];
#pragma unroll
      for (int off = 32; off > 0; off >>= 1) s += __shfl_xor(s, off);
    }
    if (lane == 0) sc[m] = s;
    const float Mn = fmaxf(M, s);
    Z = Z * fexp(M - Mn) + fexp(s - Mn);
    M = Mn;
    const float svg = s + gum[m];
    const unsigned long long key =
        ((unsigned long long)fkey(svg) << 32) | (unsigned)(NITEMS - m);
    kbest = (key > kbest) ? key : kbest;
  }
  if (lane == 0) { wm[w] = M; wz[w] = Z; wk[w] = kbest; }
  __syncthreads();
  if (tid == 0) {
    float Mb = fmaxf(fmaxf(wm[0], wm[1]), fmaxf(wm[2], wm[3]));
    float Zb = wz[0] * expf(wm[0] - Mb) + wz[1] * expf(wm[1] - Mb) +
               wz[2] * expf(wm[2] - Mb) + wz[3] * expf(wm[3] - Mb);
    unsigned long long kb = wk[0];
    kb = (wk[1] > kb) ? wk[1] : kb;
    kb = (wk[2] > kb) ? wk[2] : kb;
    kb = (wk[3] > kb) ? wk[3] : kb;
    bm[blockIdx.x] = Mb;
    bZ[blockIdx.x] = Zb;
    bkey[blockIdx.x] = kb;
  }
}

__launch_bounds__(512)
__global__ void k_step_final(const float* __restrict__ sc, const float* __restrict__ bm,
                             const float* __restrict__ bZ,
                             const unsigned long long* __restrict__ bkey,
                             int* __restrict__ sel, int* __restrict__ done, float* __restrict__ x,
                             const float* __restrict__ attn_mem, const float* __restrict__ stoprow,
                             float* __restrict__ outbuf, int t) {
  __shared__ float ra[512];
  __shared__ unsigned long long rk[512];
  __shared__ float s_M;
  __shared__ int s_out, s_copy;
  const int tid = threadIdx.x;
  float m0 = fmaxf(fmaxf(bm[tid], bm[tid + 512]), fmaxf(bm[tid + 1024], bm[tid + 1536]));
  unsigned long long k0 = bkey[tid], k1 = bkey[tid + 512], k2 = bkey[tid + 1024], k3 = bkey[tid + 1536];
  k0 = (k1 > k0) ? k1 : k0;
  k2 = (k3 > k2) ? k3 : k2;
  ra[tid] = m0;
  rk[tid] = (k2 > k0) ? k2 : k0;
  __syncthreads();
  for (int s2 = 256; s2 > 0; s2 >>= 1) {
    if (tid < s2) {
      ra[tid] = fmaxf(ra[tid], ra[tid + s2]);
      rk[tid] = (rk[tid + s2] > rk[tid]) ? rk[tid + s2] : rk[tid];
    }
    __syncthreads();
  }
  if (tid == 0) s_M = ra[0];
  __syncthreads();
  const float M = s_M;
  float zz = 0.f;
#pragma unroll
  for (int j = 0; j < 4; ++j) zz += bZ[tid + 512 * j] * expf(bm[tid + 512 * j] - M);
  ra[tid] = zz;
  __syncthreads();
  for (int s2 = 256; s2 > 0; s2 >>= 1) {
    if (tid < s2) ra[tid] += ra[tid + s2];
    __syncthreads();
  }
  if (tid == 0) {
    const float Z = ra[0];
    const unsigned long long key = rk[0];
    const int out = NITEMS - (int)(unsigned)(key & 0xFFFFFFFFull);
    const int dn = *done;
    const float lp = dn ? 0.f : (sc[out] - M - logf(Z));
    const int orec = dn ? NITEMS : out;
    if (!dn) sel[out] = 1;
    const int nd = dn || (out == NITEMS);
    *done = nd;
    outbuf[t] = (float)orec;
    outbuf[TT + t] = lp;
    s_out = out;
    s_copy = !nd;
  }
  __syncthreads();
  if (s_copy) x[tid] = (s_out < NITEMS) ? attn_mem[(size_t)s_out * DD + tid] : stoprow[tid];
}

// ======================================================================
extern "C" void kernel_launch(void* const* d_in, const int* in_sizes, int n_in,
                              void* d_out, int out_size, void* d_ws, size_t ws_size,
                              hipStream_t stream) {
  const float* attn_mem = (const float*)d_in[0];
  const float* stoprow  = (const float*)d_in[1];
  const float* init_h   = (const float*)d_in[2];
  const float* init_c   = (const float*)d_in[3];
  const float* init_i   = (const float*)d_in[4];
  const float* attn_wm  = (const float*)d_in[5];
  const float* attn_wq  = (const float*)d_in[6];
  const float* attn_v   = (const float*)d_in[7];
  const float* hop_wm   = (const float*)d_in[8];
  const float* hop_wq   = (const float*)d_in[9];
  const float* hop_v    = (const float*)d_in[10];
  const float* w_ih     = (const float*)d_in[11];
  const float* w_hh     = (const float*)d_in[12];
  const float* b_ih     = (const float*)d_in[13];
  const float* b_hh     = (const float*)d_in[14];
  const float* gumbel   = (const float*)d_in[15];

  float* ws = (float*)d_ws;
  size_t fo = 0;
  const size_t F = (size_t)NROWS * HH;
  float* attn_feat = ws + fo; fo += F;
  float* hop_feat  = ws + fo; fo += F;
  float* sc  = ws + fo; fo += 50008;
  int* sel   = (int*)(ws + fo); fo += 50008;
  float* qp  = ws + fo; fo += (size_t)NWAVE_HOP * HH;   // superset (fallback needs 4096*512)
  float* bmh = ws + fo; fo += NWAVE_HOP;
  float* bZh = ws + fo; fo += NWAVE_HOP;
  float* bma = ws + fo; fo += NBLK_ATTN;
  float* bZa = ws + fo; fo += NBLK_ATTN;
  unsigned long long* bkey = (unsigned long long*)(ws + fo); fo += 2 * NBLK_ATTN;
  float* gates = ws + fo; fo += 4 * HH;
  float* hv  = ws + fo; fo += HH;
  float* cv0 = ws + fo; fo += HH;
  float* cv1 = ws + fo; fo += HH;
  float* b1  = ws + fo; fo += HH;
  float* b2  = ws + fo; fo += HH;
  float* xv  = ws + fo; fo += HH;
  float* hA  = ws + fo; fo += HH;
  float* hB  = ws + fo; fo += HH;
  float* cv  = ws + fo; fo += HH;
  float* qn  = ws + fo; fo += HH;
  int* done2 = (int*)(ws + fo); fo += 2;
  int* xrow2 = (int*)(ws + fo); fo += 2;
  int* done  = (int*)(ws + fo); fo += 2;
  if (fo * sizeof(float) > ws_size) return;

  float* outf = (float*)d_out;

  dim3 ggrid(4, (NROWS + 127) / 128);
  k_feat_gemm<<<ggrid, 256, 0, stream>>>(attn_mem, stoprow, attn_wm, attn_feat);
  k_feat_gemm<<<ggrid, 256, 0, stream>>>(attn_mem, stoprow, hop_wm, hop_feat);

  P prm;
  prm.attn_mem = attn_mem; prm.stoprow = stoprow;
  prm.init_h = init_h; prm.init_c = init_c; prm.init_i = init_i;
  prm.attn_wq = attn_wq; prm.attn_v = attn_v;
  prm.hop_wq = hop_wq; prm.hop_v = hop_v;
  prm.w_ih = w_ih; prm.w_hh = w_hh; prm.b_ih = b_ih; prm.b_hh = b_hh;
  prm.gumbel = gumbel;
  prm.attn_feat = attn_feat; prm.hop_feat = hop_feat;
  prm.sc = sc; prm.sel = sel;
  prm.qp = qp; prm.bmh = bmh; prm.bZh = bZh; prm.bma = bma; prm.bZa = bZa;
  prm.bkey = bkey;
  prm.gates = gates; prm.hv = hv; prm.cv0 = cv0; prm.cv1 = cv1;
  prm.b1 = b1; prm.b2 = b2;
  prm.done2 = done2; prm.xrow2 = xrow2;
  prm.outf = outf;

  void* args[] = {&prm};
  hipError_t err = hipLaunchCooperativeKernel((void*)k_loop, dim3(NB), dim3(NT), args, 0, stream);

  if (err != hipSuccess) {
    // -------- discrete fallback (verified R3 path) --------
    k_init<<<(NROWS + 255) / 256, 256, 0, stream>>>(sel, xv, hA, cv, done, init_i, init_h, init_c);
    for (int t = 0; t < TT; ++t) {
      const float* hin = (t & 1) ? hB : hA;
      float* hout = (t & 1) ? hA : hB;
      k_lstm_step<<<HH, 256, 0, stream>>>(xv, hin, hout, cv, w_ih, w_hh, b_ih, b_hh);
      k_gemv<<<8, 256, 0, stream>>>(hout, hop_wq, b1);
      k_hop_fused<<<NWAVE_HOP / 4, 256, 0, stream>>>(hop_feat, b1, hop_v, qp, bmh, bZh);
      k_hop_qn<<<16, 1024, 0, stream>>>(qp, bmh, bZh, qn);
      k_gemv<<<8, 256, 0, stream>>>(qn, attn_wq, b2);
      k_attn_fused<<<NBLK_ATTN, 256, 0, stream>>>(attn_feat, b2, attn_v, sel,
                                                  gumbel + (size_t)t * NROWS, sc, bma, bZa, bkey);
      k_step_final<<<1, 512, 0, stream>>>(sc, bma, bZa, bkey, sel, done, xv,
                                          attn_mem, stoprow, outf, t);
    }
  }
}

// Round 6
// 2660.532 us; speedup vs baseline: 2.0735x; 2.0735x over previous
//
#include <hip/hip_runtime.h>
#include <math.h>

#define NITEMS 50000
#define NROWS 50001
#define NP 50048          // padded column count for transposed feat
#define DD 512
#define HH 512
#define TT 16
#define NEGV (-1e18f)
#define NGRP 782          // ceil(50001/64) row-groups for attnT
#define HOPBLK 2048       // hop grid blocks (x4 waves = 8192 waves)

typedef unsigned long long ull;

// ---- order-preserving float <-> uint key ----
__device__ __forceinline__ unsigned fkey(float f) {
  unsigned u = __float_as_uint(f);
  return (u & 0x80000000u) ? ~u : (u | 0x80000000u);
}

// fast tanh / exp via v_exp_f32 + v_rcp_f32
__device__ __forceinline__ float ftanh(float x) {
  float e = __builtin_amdgcn_exp2f(x * 2.885390081777927f);  // exp(2x)
  return 1.f - 2.f * __builtin_amdgcn_rcpf(e + 1.f);
}
__device__ __forceinline__ float fexp(float x) {
  return __builtin_amdgcn_exp2f(x * 1.4426950408889634f);
}

// ---------------- feat = mem @ W ; TR=1 stores transposed [n][m] into NP-padded buffer ----
template <int TR>
__launch_bounds__(256)
__global__ void k_feat_gemm(const float* __restrict__ A0, const float* __restrict__ stoprow,
                            const float* __restrict__ B, float* __restrict__ C) {
  __shared__ float As[8][128];
  __shared__ float Bs[8][128];
  const int tid = threadIdx.x;
  const int m0 = blockIdx.y * 128, n0 = blockIdx.x * 128;
  const int tx = tid & 15, ty = tid >> 4;
  const int ar = tid >> 1, ak = (tid & 1) * 4;
  const int bk = tid >> 5, bc = (tid & 31) * 4;
  const int arow = m0 + ar;
  const float* Arow = (arow < NITEMS) ? (A0 + (size_t)arow * DD) : stoprow;
  const bool avalid = (arow < NROWS);
  float acc[8][8];
#pragma unroll
  for (int i = 0; i < 8; ++i)
#pragma unroll
    for (int j = 0; j < 8; ++j) acc[i][j] = 0.f;

  for (int kt = 0; kt < DD; kt += 8) {
    float4 av = avalid ? *(const float4*)(Arow + kt + ak) : make_float4(0.f, 0.f, 0.f, 0.f);
    As[ak + 0][ar] = av.x;
    As[ak + 1][ar] = av.y;
    As[ak + 2][ar] = av.z;
    As[ak + 3][ar] = av.w;
    *(float4*)&Bs[bk][bc] = *(const float4*)(B + (size_t)(kt + bk) * HH + n0 + bc);
    __syncthreads();
#pragma unroll
    for (int k = 0; k < 8; ++k) {
      float a[8], b[8];
      *(float4*)&a[0] = *(const float4*)&As[k][ty * 8];
      *(float4*)&a[4] = *(const float4*)&As[k][ty * 8 + 4];
      *(float4*)&b[0] = *(const float4*)&Bs[k][tx * 4];
      *(float4*)&b[4] = *(const float4*)&Bs[k][64 + tx * 4];
#pragma unroll
      for (int i = 0; i < 8; ++i)
#pragma unroll
        for (int j = 0; j < 8; ++j) acc[i][j] = fmaf(a[i], b[j], acc[i][j]);
    }
    __syncthreads();
  }
  if (TR) {
    // featT[n][m]; pad rows (acc==0) written too — provides zero padding.
#pragma unroll
    for (int j = 0; j < 8; ++j) {
      const int n = (j < 4) ? (n0 + tx * 4 + j) : (n0 + 64 + tx * 4 + (j - 4));
      float* cp = C + (size_t)n * NP + m0 + ty * 8;
      *(float4*)cp = make_float4(acc[0][j], acc[1][j], acc[2][j], acc[3][j]);
      *(float4*)(cp + 4) = make_float4(acc[4][j], acc[5][j], acc[6][j], acc[7][j]);
    }
  } else {
#pragma unroll
    for (int i = 0; i < 8; ++i) {
      int row = m0 + ty * 8 + i;
      if (row < NROWS) {
        float* crow = C + (size_t)row * HH + n0;
        *(float4*)(crow + tx * 4) = make_float4(acc[i][0], acc[i][1], acc[i][2], acc[i][3]);
        *(float4*)(crow + 64 + tx * 4) = make_float4(acc[i][4], acc[i][5], acc[i][6], acc[i][7]);
      }
    }
  }
}

// ---------------- zero sel ----------------
__global__ void k_zero(int* __restrict__ sel) {
  int i = blockIdx.x * 256 + threadIdx.x;
  if (i < NROWS) sel[i] = 0;
}

// ---------------- finalize prev step (redundant in all blocks) + LSTM gates ----------------
__launch_bounds__(256)
__global__ void k_final_gates(const float* __restrict__ bma, const float* __restrict__ bZa,
                              const ull* __restrict__ bkey, const float* __restrict__ sc,
                              int* __restrict__ sel, int* __restrict__ done2,
                              int* __restrict__ xrow2, float* __restrict__ outf,
                              const float* __restrict__ attn_mem, const float* __restrict__ stoprow,
                              const float* __restrict__ init_i, const float* __restrict__ init_h,
                              const float* __restrict__ hv,
                              const float* __restrict__ w_ih, const float* __restrict__ w_hh,
                              const float* __restrict__ b_ih, const float* __restrict__ b_hh,
                              float* __restrict__ gates, int t) {
  __shared__ float redm[256], redz[256];
  __shared__ ull redk[256];
  const int tid = threadIdx.x, blk = blockIdx.x;
  const int w = tid >> 6, lane = tid & 63;
  int xrow = -1;
  if (t > 0) {
    float Ml = -3.0e38f;
    ull Kl = 0;
    for (int i = tid; i < NGRP; i += 256) {
      Ml = fmaxf(Ml, bma[i]);
      ull k = bkey[i];
      if (k > Kl) Kl = k;
    }
    redm[tid] = Ml;
    redk[tid] = Kl;
    __syncthreads();
    for (int s2 = 128; s2 > 0; s2 >>= 1) {
      if (tid < s2) {
        redm[tid] = fmaxf(redm[tid], redm[tid + s2]);
        if (redk[tid + s2] > redk[tid]) redk[tid] = redk[tid + s2];
      }
      __syncthreads();
    }
    const float M = redm[0];
    const ull K = redk[0];
    __syncthreads();
    float Zl = 0.f;
    for (int i = tid; i < NGRP; i += 256) Zl += bZa[i] * expf(bma[i] - M);
    redz[tid] = Zl;
    __syncthreads();
    for (int s2 = 128; s2 > 0; s2 >>= 1) {
      if (tid < s2) redz[tid] += redz[tid + s2];
      __syncthreads();
    }
    const float Z = redz[0];
    const int out = NITEMS - (int)(unsigned)(K & 0xffffffffull);
    const int d_in = (t == 1) ? 0 : done2[(t - 1) & 1];
    const int xprev = (t == 1) ? -1 : xrow2[(t - 1) & 1];
    const int nd = d_in | (out == NITEMS);
    xrow = nd ? xprev : out;
    if (blk == 0 && tid == 0) {
      outf[t - 1] = (float)(d_in ? NITEMS : out);
      outf[TT + t - 1] = d_in ? 0.f : (sc[out] - M - logf(Z));
      if (!d_in) sel[out] = 1;
      done2[t & 1] = nd;
      xrow2[t & 1] = xrow;
    }
  }
  // LSTM gate row r = blk*4 + w  (512 blocks x 4 waves = 2048 rows)
  const int r = blk * 4 + w;
  const float* xp = (xrow < 0) ? init_i
                               : ((xrow == NITEMS) ? stoprow : attn_mem + (size_t)xrow * DD);
  const float* hp = (t == 0) ? init_h : hv;
  const float4* x4 = (const float4*)xp;
  const float4* h4 = (const float4*)hp;
  const float4* wi = (const float4*)(w_ih + (size_t)r * DD);
  const float4* wh = (const float4*)(w_hh + (size_t)r * DD);
  float s = 0.f;
  float4 a, ww;
  a = x4[lane * 2];     ww = wi[lane * 2];     s += a.x * ww.x + a.y * ww.y + a.z * ww.z + a.w * ww.w;
  a = x4[lane * 2 + 1]; ww = wi[lane * 2 + 1]; s += a.x * ww.x + a.y * ww.y + a.z * ww.z + a.w * ww.w;
  a = h4[lane * 2];     ww = wh[lane * 2];     s += a.x * ww.x + a.y * ww.y + a.z * ww.z + a.w * ww.w;
  a = h4[lane * 2 + 1]; ww = wh[lane * 2 + 1]; s += a.x * ww.x + a.y * ww.y + a.z * ww.z + a.w * ww.w;
#pragma unroll
  for (int off = 32; off > 0; off >>= 1) s += __shfl_xor(s, off);
  if (lane == 0) gates[r] = s + b_ih[r] + b_hh[r];
}

// ---------------- h,c update (redundant x8) + b1 = h @ hop_wq ----------------
__launch_bounds__(256)
__global__ void k_hc_b1(const float* __restrict__ gates, const float* __restrict__ init_c,
                        float* __restrict__ cv0, float* __restrict__ cv1, float* __restrict__ hv,
                        const float* __restrict__ hop_wq, float* __restrict__ b1, int t) {
  __shared__ float h[512];
  __shared__ float red[256];
  const int tid = threadIdx.x, blk = blockIdx.x;
  const float* csrc = (t == 0) ? init_c : ((t & 1) ? cv1 : cv0);
  float* cdst = (t & 1) ? cv0 : cv1;
  for (int i = tid; i < 512; i += 256) {
    float gi = gates[i], gf = gates[512 + i], gg = gates[1024 + i], go = gates[1536 + i];
    float si = 1.f / (1.f + expf(-gi));
    float sf = 1.f / (1.f + expf(-gf));
    float so = 1.f / (1.f + expf(-go));
    float cn = sf * csrc[i] + si * tanhf(gg);
    float hval = so * tanhf(cn);
    h[i] = hval;
    if (blk == 0) { cdst[i] = cn; hv[i] = hval; }
  }
  __syncthreads();
  const int cc = tid & 63, q = tid >> 6;
  const int j = blk * 64 + cc;
  float pb = 0.f;
  for (int i = q * 128; i < q * 128 + 128; ++i) pb = fmaf(h[i], hop_wq[(size_t)i * HH + j], pb);
  red[tid] = pb;
  __syncthreads();
  if (tid < 64) b1[blk * 64 + tid] = red[tid] + red[tid + 64] + red[tid + 128] + red[tid + 192];
}

// ---------------- hop: fused score + online-softmax weighted sum (8192 waves) ----------------
__launch_bounds__(256)
__global__ void k_hop(const float* __restrict__ feat, const float* __restrict__ bvec,
                      const float* __restrict__ v, float* __restrict__ qp,
                      float* __restrict__ bmh, float* __restrict__ bZh) {
  __shared__ float smax[4], sz[4];
  __shared__ float qbuf[4][512];
  const int tid = threadIdx.x, blk = blockIdx.x;
  const int w = tid >> 6, lane = tid & 63;
  const int wv = blk * 4 + w;
  float bv[8], vv[8], qa[8];
#pragma unroll
  for (int j = 0; j < 8; ++j) { bv[j] = bvec[lane * 8 + j]; vv[j] = v[lane * 8 + j]; qa[j] = 0.f; }
  float M = -3.0e38f, Z = 0.f;
  for (int m = wv; m < NROWS; m += 4 * HOPBLK) {
    const float4* fp = (const float4*)(feat + (size_t)m * HH);
    float4 A = fp[lane * 2], B = fp[lane * 2 + 1];
    float f[8] = {A.x, A.y, A.z, A.w, B.x, B.y, B.z, B.w};
    float s = 0.f;
#pragma unroll
    for (int j = 0; j < 8; ++j) s += ftanh(f[j] + bv[j]) * vv[j];
#pragma unroll
    for (int off = 32; off > 0; off >>= 1) s += __shfl_xor(s, off);
    const float Mn = fmaxf(M, s);
    const float scale = fexp(M - Mn), e = fexp(s - Mn);
    Z = Z * scale + e;
#pragma unroll
    for (int j = 0; j < 8; ++j) qa[j] = fmaf(e, f[j], qa[j] * scale);
    M = Mn;
  }
  if (lane == 0) { smax[w] = M; sz[w] = Z; }
  __syncthreads();
  float Mb = fmaxf(fmaxf(smax[0], smax[1]), fmaxf(smax[2], smax[3]));
  const float sw = fexp(M - Mb);
#pragma unroll
  for (int j = 0; j < 8; ++j) qbuf[w][lane * 8 + j] = qa[j] * sw;
  __syncthreads();
  float a0 = 0.f, a1 = 0.f;
#pragma unroll
  for (int w2 = 0; w2 < 4; ++w2) { a0 += qbuf[w2][tid]; a1 += qbuf[w2][tid + 256]; }
  qp[(size_t)blk * 512 + tid] = a0;
  qp[(size_t)blk * 512 + tid + 256] = a1;
  if (tid == 0) {
    float Zb = 0.f;
#pragma unroll
    for (int w2 = 0; w2 < 4; ++w2) Zb += sz[w2] * expf(smax[w2] - Mb);
    bmh[blk] = Mb;
    bZh[blk] = Zb;
  }
}

// ---------------- combine 2048 hop partials -> qn ----------------
__launch_bounds__(1024)
__global__ void k_qn(const float* __restrict__ qp, const float* __restrict__ bmh,
                     const float* __restrict__ bZh, float* __restrict__ qn) {
  __shared__ float red[1024];
  __shared__ float cf[HOPBLK];
  const int tid = threadIdx.x;
  red[tid] = fmaxf(bmh[tid], bmh[tid + 1024]);
  __syncthreads();
  for (int s2 = 512; s2 > 0; s2 >>= 1) {
    if (tid < s2) red[tid] = fmaxf(red[tid], red[tid + s2]);
    __syncthreads();
  }
  const float Mg = red[0];
  __syncthreads();
  float c0 = expf(bmh[tid] - Mg), c1 = expf(bmh[tid + 1024] - Mg);
  cf[tid] = c0;
  cf[tid + 1024] = c1;
  red[tid] = bZh[tid] * c0 + bZh[tid + 1024] * c1;
  __syncthreads();
  for (int s2 = 512; s2 > 0; s2 >>= 1) {
    if (tid < s2) red[tid] += red[tid + s2];
    __syncthreads();
  }
  const float Z = red[0];
  __syncthreads();
  const int cc = tid & 31, q = tid >> 5;  // q: 0..31
  const int col = blockIdx.x * 32 + cc;
  float acc = 0.f;
  for (int p = q * 64; p < q * 64 + 64; ++p) acc = fmaf(cf[p], qp[(size_t)p * 512 + col], acc);
  red[tid] = acc;
  __syncthreads();
  if (tid < 32) {
    float a = 0.f;
#pragma unroll
    for (int g = 0; g < 32; ++g) a += red[tid + 32 * g];
    qn[blockIdx.x * 32 + tid] = a / Z;
  }
}

// ---------------- b2[j] = sum_i qn[i] * W[i][j] ----------------
__launch_bounds__(256)
__global__ void k_gemv(const float* __restrict__ q, const float* __restrict__ W,
                       float* __restrict__ out) {
  __shared__ float lds[256];
  const int tid = threadIdx.x;
  const int cc = tid & 63, rs = tid >> 6;
  const int j = blockIdx.x * 64 + cc;
  float p = 0.f;
  for (int i = rs * 128; i < rs * 128 + 128; ++i) p += q[i] * W[(size_t)i * HH + j];
  lds[tid] = p;
  __syncthreads();
  if (tid < 64) out[blockIdx.x * 64 + tid] = lds[tid] + lds[tid + 64] + lds[tid + 128] + lds[tid + 192];
}

// ---------------- attn: transposed sweep — 64 rows/wave-group, no per-row shuffles ----------------
__launch_bounds__(256)
__global__ void k_attnT(const float* __restrict__ featT, const float* __restrict__ b2,
                        const float* __restrict__ av, const int* __restrict__ sel,
                        const float* __restrict__ gum, float* __restrict__ sc,
                        float* __restrict__ bma, float* __restrict__ bZa, ull* __restrict__ bkey) {
  __shared__ float spart[4][64];
  const int tid = threadIdx.x, g = blockIdx.x;
  const int w = tid >> 6, lane = tid & 63;
  const int m = g * 64 + lane;   // < NP always (padded)
  const int h0 = w * 128;
  const float* fp = featT + (size_t)h0 * NP + m;
  float acc = 0.f;
#pragma unroll 8
  for (int hh = 0; hh < 128; ++hh) {
    float f = *fp;
    fp += NP;
    acc += ftanh(f + b2[h0 + hh]) * av[h0 + hh];
  }
  spart[w][lane] = acc;
  __syncthreads();
  if (w == 0) {
    float s = spart[0][lane] + spart[1][lane] + spart[2][lane] + spart[3][lane];
    const bool valid = (m < NROWS);
    float M, Z;
    ull key;
    if (valid) {
      float se = sel[m] ? NEGV : s;
      sc[m] = se;
      key = ((ull)fkey(se + gum[m]) << 32) | (unsigned)(NITEMS - m);
      M = se;
      Z = 1.f;
    } else {
      key = 0;
      M = -3.0e38f;
      Z = 0.f;
    }
#pragma unroll
    for (int off = 32; off > 0; off >>= 1) {
      float Mo = __shfl_xor(M, off);
      float Zo = __shfl_xor(Z, off);
      ull Ko = __shfl_xor(key, off);
      float Mn = fmaxf(M, Mo);
      Z = Z * fexp(M - Mn) + Zo * fexp(Mo - Mn);
      M = Mn;
      if (Ko > key) key = Ko;
    }
    if (lane == 0) { bma[g] = M; bZa[g] = Z; bkey[g] = key; }
  }
}

// ---------------- final outputs for step 15 ----------------
__launch_bounds__(256)
__global__ void k_tail(const float* __restrict__ bma, const float* __restrict__ bZa,
                       const ull* __restrict__ bkey, const float* __restrict__ sc,
                       const int* __restrict__ done2, float* __restrict__ outf) {
  __shared__ float redm[256], redz[256];
  __shared__ ull redk[256];
  const int tid = threadIdx.x;
  float Ml = -3.0e38f;
  ull Kl = 0;
  for (int i = tid; i < NGRP; i += 256) {
    Ml = fmaxf(Ml, bma[i]);
    ull k = bkey[i];
    if (k > Kl) Kl = k;
  }
  redm[tid] = Ml;
  redk[tid] = Kl;
  __syncthreads();
  for (int s2 = 128; s2 > 0; s2 >>= 1) {
    if (tid < s2) {
      redm[tid] = fmaxf(redm[tid], redm[tid + s2]);
      if (redk[tid + s2] > redk[tid]) redk[tid] = redk[tid + s2];
    }
    __syncthreads();
  }
  const float M = redm[0];
  const ull K = redk[0];
  __syncthreads();
  float Zl = 0.f;
  for (int i = tid; i < NGRP; i += 256) Zl += bZa[i] * expf(bma[i] - M);
  redz[tid] = Zl;
  __syncthreads();
  for (int s2 = 128; s2 > 0; s2 >>= 1) {
    if (tid < s2) redz[tid] += redz[tid + s2];
    __syncthreads();
  }
  if (tid == 0) {
    const float Z = redz[0];
    const int out = NITEMS - (int)(unsigned)(K & 0xffffffffull);
    const int d_in = done2[(TT - 1) & 1];
    outf[TT - 1] = (float)(d_in ? NITEMS : out);
    outf[2 * TT - 1] = d_in ? 0.f : (sc[out] - M - logf(Z));
  }
}

// ======================================================================
extern "C" void kernel_launch(void* const* d_in, const int* in_sizes, int n_in,
                              void* d_out, int out_size, void* d_ws, size_t ws_size,
                              hipStream_t stream) {
  const float* attn_mem = (const float*)d_in[0];
  const float* stoprow  = (const float*)d_in[1];
  const float* init_h   = (const float*)d_in[2];
  const float* init_c   = (const float*)d_in[3];
  const float* init_i   = (const float*)d_in[4];
  const float* attn_wm  = (const float*)d_in[5];
  const float* attn_wq  = (const float*)d_in[6];
  const float* attn_v   = (const float*)d_in[7];
  const float* hop_wm   = (const float*)d_in[8];
  const float* hop_wq   = (const float*)d_in[9];
  const float* hop_v    = (const float*)d_in[10];
  const float* w_ih     = (const float*)d_in[11];
  const float* w_hh     = (const float*)d_in[12];
  const float* b_ih     = (const float*)d_in[13];
  const float* b_hh     = (const float*)d_in[14];
  const float* gumbel   = (const float*)d_in[15];

  float* ws = (float*)d_ws;
  size_t fo = 0;
  float* hop_feat   = ws + fo; fo += (size_t)NROWS * HH;   // normal layout
  float* attn_featT = ws + fo; fo += (size_t)HH * NP;      // transposed, padded
  float* sc  = ws + fo; fo += 50048;
  int* sel   = (int*)(ws + fo); fo += 50048;
  float* qp  = ws + fo; fo += (size_t)HOPBLK * 512;
  float* bmh = ws + fo; fo += HOPBLK;
  float* bZh = ws + fo; fo += HOPBLK;
  float* bma = ws + fo; fo += 1024;
  float* bZa = ws + fo; fo += 1024;
  ull* bkey  = (ull*)(ws + fo); fo += 2048;
  float* gates = ws + fo; fo += 4 * HH;
  float* hv  = ws + fo; fo += HH;
  float* cv0 = ws + fo; fo += HH;
  float* cv1 = ws + fo; fo += HH;
  float* b1  = ws + fo; fo += HH;
  float* b2  = ws + fo; fo += HH;
  float* qn  = ws + fo; fo += HH;
  int* done2 = (int*)(ws + fo); fo += 2;
  int* xrow2 = (int*)(ws + fo); fo += 2;
  if (fo * sizeof(float) > ws_size) return;

  float* outf = (float*)d_out;

  k_zero<<<196, 256, 0, stream>>>(sel);
  dim3 ggrid(4, (NP + 127) / 128);  // 391 m-tiles covers 50048 exactly
  k_feat_gemm<1><<<ggrid, 256, 0, stream>>>(attn_mem, stoprow, attn_wm, attn_featT);
  k_feat_gemm<0><<<ggrid, 256, 0, stream>>>(attn_mem, stoprow, hop_wm, hop_feat);

  for (int t = 0; t < TT; ++t) {
    k_final_gates<<<512, 256, 0, stream>>>(bma, bZa, bkey, sc, sel, done2, xrow2, outf,
                                           attn_mem, stoprow, init_i, init_h, hv,
                                           w_ih, w_hh, b_ih, b_hh, gates, t);
    k_hc_b1<<<8, 256, 0, stream>>>(gates, init_c, cv0, cv1, hv, hop_wq, b1, t);
    k_hop<<<HOPBLK, 256, 0, stream>>>(hop_feat, b1, hop_v, qp, bmh, bZh);
    k_qn<<<16, 1024, 0, stream>>>(qp, bmh, bZh, qn);
    k_gemv<<<8, 256, 0, stream>>>(qn, attn_wq, b2);
    k_attnT<<<NGRP, 256, 0, stream>>>(attn_featT, b2, attn_v, sel,
                                      gumbel + (size_t)t * NROWS, sc, bma, bZa, bkey);
  }
  k_tail<<<1, 256, 0, stream>>>(bma, bZa, bkey, sc, done2, outf);
}